// Round 1
// baseline (2890.985 us; speedup 1.0000x reference)
//
#include <hip/hip_runtime.h>
#include <cstddef>

#define HEADS   8
#define DHEAD   64
#define MAXPOS  512
#define DIM     512
#define INNER   512
#define NSEQ    2048
#define BATCH   4

static constexpr float SCALE = 0.125f;  // DIM_HEAD^-0.5

// ---------------------------------------------------------------------------
// Generic tiled fp32 GEMM: C[M,Nc] = (A[M,K] @ W[K,Nc]) * scale (+ bias)
// BM=BN=64, BK=16, 256 threads, 4x4 microtile per thread.
// ---------------------------------------------------------------------------
__global__ __launch_bounds__(256) void gemm_f32_kernel(
    const float* __restrict__ A, const float* __restrict__ W,
    float* __restrict__ C, int M, int K, int Nc,
    const float* __restrict__ bias, float scale)
{
    __shared__ float As[16][68];   // [k][m], stride 68 floats (272B, 16B-aligned)
    __shared__ float Ws[16][68];   // [k][n]

    const int tid = threadIdx.x;
    const int tx = tid & 15;       // 16 cols of threads
    const int ty = tid >> 4;       // 16 rows of threads
    const int m0 = blockIdx.y * 64;
    const int n0 = blockIdx.x * 64;

    float acc[4][4] = {};

    for (int k0 = 0; k0 < K; k0 += 16) {
        // Load A tile (64 rows x 16 cols) -> As[k][m]
        #pragma unroll
        for (int i = 0; i < 4; ++i) {
            int e = i * 256 + tid;
            int m = e >> 4, k = e & 15;
            As[k][m] = A[(size_t)(m0 + m) * K + (k0 + k)];
        }
        // Load W tile (16 rows x 64 cols) -> Ws[k][n]
        #pragma unroll
        for (int i = 0; i < 4; ++i) {
            int e = i * 256 + tid;
            int k = e >> 6, n = e & 63;
            Ws[k][n] = W[(size_t)(k0 + k) * Nc + (n0 + n)];
        }
        __syncthreads();

        #pragma unroll
        for (int kk = 0; kk < 16; ++kk) {
            float4 a = *(const float4*)&As[kk][ty * 4];
            float4 w = *(const float4*)&Ws[kk][tx * 4];
            acc[0][0] += a.x * w.x; acc[0][1] += a.x * w.y; acc[0][2] += a.x * w.z; acc[0][3] += a.x * w.w;
            acc[1][0] += a.y * w.x; acc[1][1] += a.y * w.y; acc[1][2] += a.y * w.z; acc[1][3] += a.y * w.w;
            acc[2][0] += a.z * w.x; acc[2][1] += a.z * w.y; acc[2][2] += a.z * w.z; acc[2][3] += a.z * w.w;
            acc[3][0] += a.w * w.x; acc[3][1] += a.w * w.y; acc[3][2] += a.w * w.z; acc[3][3] += a.w * w.w;
        }
        __syncthreads();
    }

    float4 b4 = make_float4(0.f, 0.f, 0.f, 0.f);
    if (bias != nullptr) b4 = *(const float4*)&bias[n0 + tx * 4];

    #pragma unroll
    for (int i = 0; i < 4; ++i) {
        float4 r;
        r.x = acc[i][0] * scale + b4.x;
        r.y = acc[i][1] * scale + b4.y;
        r.z = acc[i][2] * scale + b4.z;
        r.w = acc[i][3] * scale + b4.w;
        *(float4*)&C[(size_t)(m0 + ty * 4 + i) * Nc + n0 + tx * 4] = r;
    }
}

// ---------------------------------------------------------------------------
// Flash attention with relative positions, fp32.
// Block = (b, h, 32-query tile). 256 threads (16x16 grid).
// Scores: rows = ty*2+{0,1}, key cols = tx + 16*j  (j=0..3)  [bank-friendly]
// PV/out: rows = ty*2+{0,1}, d cols  = tx*4 + {0..3}
// s[n][r] = q[n]·(k[r] + rel_emb[clip(n-r)+512])   (q pre-scaled by SCALE)
// ---------------------------------------------------------------------------
#define QB 32
#define KB 64

__global__ __launch_bounds__(256) void flash_rel_kernel(
    const float* __restrict__ q,    // [B,N,INNER], pre-scaled by SCALE
    const float* __restrict__ kv,   // [B,N,2*INNER]
    const float* __restrict__ rel,  // [2*MAXPOS+1, DHEAD]
    float* __restrict__ o)          // [B,N,INNER]
{
    __shared__ float qs[QB][DHEAD + 4];
    __shared__ float ks[KB][DHEAD + 4];
    __shared__ float vs[KB][DHEAD + 4];
    __shared__ float rs[96][DHEAD + 4];
    __shared__ float ps[QB][KB + 4];

    const int tid = threadIdx.x;
    const int tx = tid & 15;
    const int ty = tid >> 4;
    const int n0 = blockIdx.x * QB;
    const int h  = blockIdx.y;
    const int b  = blockIdx.z;

    const float* qbase = q  + (size_t)b * NSEQ * INNER       + (size_t)h * DHEAD;
    const float* kbase = kv + (size_t)b * NSEQ * (2 * INNER) + (size_t)h * DHEAD;
    const float* vbase = kbase + INNER;

    // Load q tile (32 x 64)
    for (int e = tid; e < QB * DHEAD; e += 256) {
        int r = e >> 6, d = e & 63;
        qs[r][d] = qbase[(size_t)(n0 + r) * INNER + d];
    }

    float m[2] = {-1e30f, -1e30f};
    float l[2] = {0.f, 0.f};
    float acc[2][4] = {};

    for (int kt = 0; kt < NSEQ / KB; ++kt) {
        const int r0 = kt * KB;
        __syncthreads();  // protect ks/vs/rs/ps from previous iteration's readers

        // Load K and V tiles (64 x 64 each), coalesced on d
        for (int e = tid; e < KB * DHEAD; e += 256) {
            int r = e >> 6, d = e & 63;
            ks[r][d] = kbase[(size_t)(r0 + r) * (2 * INNER) + d];
            vs[r][d] = vbase[(size_t)(r0 + r) * (2 * INNER) + d];
        }
        // Rel window: j in [jlo, jlo+95] covers clip(n-r)+MAXPOS for this tile pair
        const int diff_lo = n0 - r0 - (KB - 1);
        const int jlo = min(max(diff_lo, -MAXPOS), MAXPOS) + MAXPOS;
        for (int e = tid; e < 96 * DHEAD; e += 256) {
            int jj = e >> 6, d = e & 63;
            int j = min(jlo + jj, 2 * MAXPOS);
            rs[jj][d] = rel[(size_t)j * DHEAD + d];
        }
        __syncthreads();

        // ---- scores ----
        float s[2][4];
        #pragma unroll
        for (int i = 0; i < 2; ++i) {
            const int row = ty * 2 + i;
            const int n = n0 + row;
            #pragma unroll
            for (int j = 0; j < 4; ++j) {
                const int col = tx + 16 * j;
                const int rr = r0 + col;
                const int dd = min(max(n - rr, -MAXPOS), MAXPOS) + MAXPOS;
                const int jj = dd - jlo;   // in [0, 95]
                float sum = 0.f;
                #pragma unroll
                for (int d4 = 0; d4 < DHEAD; d4 += 4) {
                    float4 qv = *(const float4*)&qs[row][d4];
                    float4 kk = *(const float4*)&ks[col][d4];
                    float4 rv = *(const float4*)&rs[jj][d4];
                    sum += qv.x * (kk.x + rv.x);
                    sum += qv.y * (kk.y + rv.y);
                    sum += qv.z * (kk.z + rv.z);
                    sum += qv.w * (kk.w + rv.w);
                }
                s[i][j] = sum;
            }
        }

        // ---- online softmax ----
        #pragma unroll
        for (int i = 0; i < 2; ++i) {
            float mt = fmaxf(fmaxf(s[i][0], s[i][1]), fmaxf(s[i][2], s[i][3]));
            #pragma unroll
            for (int w = 1; w < 16; w <<= 1)
                mt = fmaxf(mt, __shfl_xor(mt, w, 64));
            const float mnew = fmaxf(m[i], mt);
            const float alpha = __expf(m[i] - mnew);
            float psum = 0.f;
            #pragma unroll
            for (int j = 0; j < 4; ++j) {
                float p = __expf(s[i][j] - mnew);
                s[i][j] = p;
                psum += p;
            }
            #pragma unroll
            for (int w = 1; w < 16; w <<= 1)
                psum += __shfl_xor(psum, w, 64);
            l[i] = l[i] * alpha + psum;
            m[i] = mnew;
            #pragma unroll
            for (int j = 0; j < 4; ++j) acc[i][j] *= alpha;
        }

        // ---- P to LDS ----
        #pragma unroll
        for (int i = 0; i < 2; ++i)
            #pragma unroll
            for (int j = 0; j < 4; ++j)
                ps[ty * 2 + i][tx + 16 * j] = s[i][j];
        __syncthreads();

        // ---- PV ----
        #pragma unroll
        for (int i = 0; i < 2; ++i) {
            const int row = ty * 2 + i;
            #pragma unroll 8
            for (int r = 0; r < KB; ++r) {
                const float p = ps[row][r];
                float4 vv = *(const float4*)&vs[r][tx * 4];
                acc[i][0] += p * vv.x;
                acc[i][1] += p * vv.y;
                acc[i][2] += p * vv.z;
                acc[i][3] += p * vv.w;
            }
        }
    }

    // ---- epilogue ----
    float* obase = o + ((size_t)b * NSEQ + n0) * INNER + (size_t)h * DHEAD;
    #pragma unroll
    for (int i = 0; i < 2; ++i) {
        const int row = ty * 2 + i;
        const float inv = 1.f / l[i];
        float4 r = make_float4(acc[i][0] * inv, acc[i][1] * inv,
                               acc[i][2] * inv, acc[i][3] * inv);
        *(float4*)&obase[(size_t)row * INNER + tx * 4] = r;
    }
}

// ---------------------------------------------------------------------------
extern "C" void kernel_launch(void* const* d_in, const int* in_sizes, int n_in,
                              void* d_out, int out_size, void* d_ws, size_t ws_size,
                              hipStream_t stream)
{
    const float* x   = (const float*)d_in[0];
    const float* Wq  = (const float*)d_in[1];
    const float* Wkv = (const float*)d_in[2];
    const float* Wo  = (const float*)d_in[3];
    const float* bo  = (const float*)d_in[4];
    const float* rel = (const float*)d_in[5];
    float* out = (float*)d_out;

    const size_t ROWS = (size_t)BATCH * NSEQ;  // 8192
    float* qbuf  = (float*)d_ws;               // [8192, 512]
    float* kvbuf = qbuf + ROWS * INNER;        // [8192, 1024]
    float* abuf  = kvbuf + ROWS * 2 * INNER;   // [8192, 512]

    dim3 blk(256);

    // q = (x @ Wq) * SCALE   (pre-scaling q scales both dots and pos terms)
    gemm_f32_kernel<<<dim3(INNER / 64, ROWS / 64), blk, 0, stream>>>(
        x, Wq, qbuf, (int)ROWS, DIM, INNER, nullptr, SCALE);
    // kv = x @ Wkv
    gemm_f32_kernel<<<dim3(2 * INNER / 64, ROWS / 64), blk, 0, stream>>>(
        x, Wkv, kvbuf, (int)ROWS, DIM, 2 * INNER, nullptr, 1.0f);
    // attention
    flash_rel_kernel<<<dim3(NSEQ / QB, HEADS, BATCH), blk, 0, stream>>>(
        qbuf, kvbuf, rel, abuf);
    // out = abuf @ Wo + bo
    gemm_f32_kernel<<<dim3(DIM / 64, ROWS / 64), blk, 0, stream>>>(
        abuf, Wo, out, (int)ROWS, INNER, DIM, bo, 1.0f);
}

// Round 2
// 581.235 us; speedup vs baseline: 4.9739x; 4.9739x over previous
//
#include <hip/hip_runtime.h>
#include <cstddef>

#define HEADS   8
#define DHEAD   64
#define MAXPOS  512
#define DIM     512
#define INNER   512
#define NSEQ    2048
#define BATCH   4

static constexpr float SCALE = 0.125f;  // DIM_HEAD^-0.5

typedef __bf16 bf16x8 __attribute__((ext_vector_type(8)));
typedef float  f32x4  __attribute__((ext_vector_type(4)));

static __device__ __forceinline__ ushort f2bf(float f) {
    union { float f; unsigned u; } v; v.f = f;
    unsigned r = v.u + 0x7FFFu + ((v.u >> 16) & 1u);   // RTNE
    return (ushort)(r >> 16);
}
static __device__ __forceinline__ float bf2f(ushort u) {
    union { unsigned u; float f; } v; v.u = ((unsigned)u) << 16;
    return v.f;
}
static __device__ __forceinline__ f32x4 mfma16(bf16x8 a, bf16x8 b, f32x4 c) {
    return __builtin_amdgcn_mfma_f32_16x16x32_bf16(a, b, c, 0, 0, 0);
}
// swizzled byte offset within a 128B-row LDS tile (spreads 16B slots over banks)
static __device__ __forceinline__ int swz(int row, int byteoff) {
    return row * 128 + (byteoff ^ ((row & 7) << 4));
}

// ---------------------------------------------------------------------------
// Tiled fp32 GEMM, 64x64x16 tile, 256 thr, 4x4 microtile.
// MODE 0: fp32 out + bias. MODE 1: bf16 out (scaled). MODE 2: kv split —
//   cols <512 -> bf16 K row-major; cols >=512 -> bf16 V transposed per head.
// ---------------------------------------------------------------------------
template <int MODE>
__global__ __launch_bounds__(256) void gemm_kernel(
    const float* __restrict__ A, const float* __restrict__ W,
    float* __restrict__ Cf, ushort* __restrict__ Cb0, ushort* __restrict__ Cb1,
    int M, int K, int Nc, const float* __restrict__ bias, float scale)
{
    __shared__ float As[16][68];
    __shared__ float Ws[16][68];

    const int tid = threadIdx.x;
    const int tx = tid & 15;
    const int ty = tid >> 4;
    const int m0 = blockIdx.y * 64;
    const int n0 = blockIdx.x * 64;

    float acc[4][4] = {};

    for (int k0 = 0; k0 < K; k0 += 16) {
        #pragma unroll
        for (int i = 0; i < 4; ++i) {
            int e = i * 256 + tid;
            int m = e >> 4, k = e & 15;
            As[k][m] = A[(size_t)(m0 + m) * K + (k0 + k)];
        }
        #pragma unroll
        for (int i = 0; i < 4; ++i) {
            int e = i * 256 + tid;
            int k = e >> 6, n = e & 63;
            Ws[k][n] = W[(size_t)(k0 + k) * Nc + (n0 + n)];
        }
        __syncthreads();
        #pragma unroll
        for (int kk = 0; kk < 16; ++kk) {
            float4 a = *(const float4*)&As[kk][ty * 4];
            float4 w = *(const float4*)&Ws[kk][tx * 4];
            acc[0][0] += a.x * w.x; acc[0][1] += a.x * w.y; acc[0][2] += a.x * w.z; acc[0][3] += a.x * w.w;
            acc[1][0] += a.y * w.x; acc[1][1] += a.y * w.y; acc[1][2] += a.y * w.z; acc[1][3] += a.y * w.w;
            acc[2][0] += a.z * w.x; acc[2][1] += a.z * w.y; acc[2][2] += a.z * w.z; acc[2][3] += a.z * w.w;
            acc[3][0] += a.w * w.x; acc[3][1] += a.w * w.y; acc[3][2] += a.w * w.z; acc[3][3] += a.w * w.w;
        }
        __syncthreads();
    }

    if (MODE == 0) {
        float4 b4 = make_float4(0.f, 0.f, 0.f, 0.f);
        if (bias != nullptr) b4 = *(const float4*)&bias[n0 + tx * 4];
        #pragma unroll
        for (int i = 0; i < 4; ++i) {
            float4 r;
            r.x = acc[i][0] * scale + b4.x;
            r.y = acc[i][1] * scale + b4.y;
            r.z = acc[i][2] * scale + b4.z;
            r.w = acc[i][3] * scale + b4.w;
            *(float4*)&Cf[(size_t)(m0 + ty * 4 + i) * Nc + n0 + tx * 4] = r;
        }
    } else if (MODE == 1) {
        #pragma unroll
        for (int i = 0; i < 4; ++i) {
            ushort4 u = make_ushort4(f2bf(acc[i][0] * scale), f2bf(acc[i][1] * scale),
                                     f2bf(acc[i][2] * scale), f2bf(acc[i][3] * scale));
            *(ushort4*)&Cb0[(size_t)(m0 + ty * 4 + i) * Nc + n0 + tx * 4] = u;
        }
    } else {
        if (n0 < INNER) {
            #pragma unroll
            for (int i = 0; i < 4; ++i) {
                ushort4 u = make_ushort4(f2bf(acc[i][0]), f2bf(acc[i][1]),
                                         f2bf(acc[i][2]), f2bf(acc[i][3]));
                *(ushort4*)&Cb0[(size_t)(m0 + ty * 4 + i) * INNER + n0 + tx * 4] = u;
            }
        } else {
            const int bb = m0 >> 11;               // token block / 2048
            const int t0 = (m0 & 2047) + ty * 4;
            #pragma unroll
            for (int j = 0; j < 4; ++j) {
                int n = n0 + tx * 4 + j - INNER;
                int hh = n >> 6, dd = n & 63;
                ushort4 u = make_ushort4(f2bf(acc[0][j]), f2bf(acc[1][j]),
                                         f2bf(acc[2][j]), f2bf(acc[3][j]));
                *(ushort4*)&Cb1[(((size_t)bb * HEADS + hh) * DHEAD + dd) * NSEQ + t0] = u;
            }
        }
    }
}

// ---------------------------------------------------------------------------
__global__ __launch_bounds__(256) void rel2bf_kernel(const float* __restrict__ rel,
                                                     ushort* __restrict__ relb)
{
    int i = blockIdx.x * 256 + threadIdx.x;
    if (i < (2 * MAXPOS + 1) * DHEAD) relb[i] = f2bf(rel[i]);
}

// ---------------------------------------------------------------------------
// MFMA flash attention with relative positions.
// Block = (b, h, 64-query tile), 256 thr = 4 waves, wave w owns q rows
// [n0+16w, n0+16w+16). K tile = 64 keys. All tiles bf16 in LDS, XOR-swizzled.
// s = (q*SCALE)·k + gather(PR),  PR = (q*SCALE)·relwin^T  via MFMA.
// ---------------------------------------------------------------------------
__global__ __launch_bounds__(256, 2) void flash_mfma_kernel(
    const ushort* __restrict__ qb,    // [B*N, 512] bf16, pre-scaled
    const ushort* __restrict__ kb,    // [B*N, 512] bf16
    const ushort* __restrict__ vtb,   // [B, H, 64, N] bf16 (V transposed)
    const ushort* __restrict__ relb,  // [1025, 64] bf16
    float* __restrict__ ob)           // [B*N, 512] f32
{
    __shared__ __attribute__((aligned(16))) char ksw[64 * 128];     // K tile
    __shared__ __attribute__((aligned(16))) char vtsw[64 * 128];    // V^T tile
    __shared__ __attribute__((aligned(16))) char relw[144 * 128];   // rel window
    __shared__ __attribute__((aligned(16))) char pswb[4][16 * 128]; // P per wave
    __shared__ ushort prs[4][16][100];                              // PR per wave

    const int tid  = threadIdx.x;
    const int w    = tid >> 6;
    const int lane = tid & 63;
    const int l15  = lane & 15;
    const int g    = lane >> 4;

    const int n0 = blockIdx.x * 64;
    const int h  = blockIdx.y;
    const int b  = blockIdx.z;

    // Q fragments (A-operand): row = l15, k = 32*ks + 8*g + j
    bf16x8 qf[2];
    {
        const int nq = n0 + w * 16 + l15;
        const ushort* qrow = qb + (size_t)(b * NSEQ + nq) * INNER + h * DHEAD;
        qf[0] = *(const bf16x8*)(qrow + 8 * g);
        qf[1] = *(const bf16x8*)(qrow + 32 + 8 * g);
    }

    const ushort* kbase  = kb + (size_t)(b * NSEQ) * INNER + h * DHEAD;
    const ushort* vtbase = vtb + (size_t)(b * HEADS + h) * DHEAD * NSEQ;

    f32x4 oacc[4];
    #pragma unroll
    for (int i = 0; i < 4; ++i) oacc[i] = (f32x4){0.f, 0.f, 0.f, 0.f};
    float mrow[4] = {-1e30f, -1e30f, -1e30f, -1e30f};
    float lrow[4] = {0.f, 0.f, 0.f, 0.f};

    for (int kt = 0; kt < NSEQ / 64; ++kt) {
        const int r0 = kt * 64;
        int dlo = n0 - r0 - 63, dhi = n0 + 63 - r0;
        int jlo = min(max(dlo, -MAXPOS), MAXPOS) + MAXPOS;
        int jhi = min(max(dhi, -MAXPOS), MAXPOS) + MAXPOS;
        int span = jhi - jlo + 1;
        int nrows = (span + 30) & ~15; if (nrows > 144) nrows = 144;

        __syncthreads();
        // ---- stage K, V^T, rel window (bf16, swizzled rows of 128B) ----
        for (int c = tid; c < 512; c += 256) {
            int row = c >> 3, sl = c & 7;
            *(int4*)(ksw + swz(row, sl * 16)) =
                *(const int4*)(kbase + (size_t)(r0 + row) * INNER + sl * 8);
        }
        for (int c = tid; c < 512; c += 256) {
            int d = c >> 3, sl = c & 7;
            *(int4*)(vtsw + swz(d, sl * 16)) =
                *(const int4*)(vtbase + (size_t)d * NSEQ + r0 + sl * 8);
        }
        for (int c = tid; c < nrows * 8; c += 256) {
            int row = c >> 3, sl = c & 7;
            int gr = jlo + row; if (gr > 2 * MAXPOS) gr = 2 * MAXPOS;
            *(int4*)(relw + swz(row, sl * 16)) =
                *(const int4*)(relb + gr * DHEAD + sl * 8);
        }
        __syncthreads();

        // ---- QK^T ----
        f32x4 sc[4];
        #pragma unroll
        for (int ct = 0; ct < 4; ++ct) {
            f32x4 a = (f32x4){0.f, 0.f, 0.f, 0.f};
            #pragma unroll
            for (int ks = 0; ks < 2; ++ks) {
                bf16x8 kf = *(const bf16x8*)(ksw + swz(16 * ct + l15, (4 * ks + g) * 16));
                a = mfma16(qf[ks], kf, a);
            }
            sc[ct] = a;
        }

        // ---- PR = Q · relwin^T over per-wave aligned sub-window ----
        const int nw0 = n0 + w * 16;
        int jlo_w = min(max(nw0 - r0 - 63, -MAXPOS), MAXPOS) + MAXPOS;
        int jhi_w = min(max(nw0 + 15 - r0, -MAXPOS), MAXPOS) + MAXPOS;
        int jbase = jlo + ((jlo_w - jlo) & ~15);
        int nct = (jhi_w - jbase + 16) >> 4;   // <= 6

        for (int c2 = 0; c2 < nct; ++c2) {
            f32x4 pr = (f32x4){0.f, 0.f, 0.f, 0.f};
            int wr = (jbase - jlo) + 16 * c2 + l15;
            #pragma unroll
            for (int ks = 0; ks < 2; ++ks) {
                bf16x8 rf = *(const bf16x8*)(relw + swz(wr, (4 * ks + g) * 16));
                pr = mfma16(qf[ks], rf, pr);
            }
            #pragma unroll
            for (int reg = 0; reg < 4; ++reg)
                prs[w][4 * g + reg][16 * c2 + l15] = f2bf(pr[reg]);
        }
        asm volatile("" ::: "memory");  // order per-wave LDS write->read

        // ---- gather pos into scores ----
        #pragma unroll
        for (int ct = 0; ct < 4; ++ct) {
            int r = r0 + 16 * ct + l15;
            #pragma unroll
            for (int reg = 0; reg < 4; ++reg) {
                int n = nw0 + 4 * g + reg;
                int dd = min(max(n - r, -MAXPOS), MAXPOS) + MAXPOS;
                sc[ct][reg] += bf2f(prs[w][4 * g + reg][dd - jbase]);
            }
        }

        // ---- online softmax (rows = 4g+reg, cols across 16 lanes x 4 ct) ----
        #pragma unroll
        for (int reg = 0; reg < 4; ++reg) {
            float mx = fmaxf(fmaxf(sc[0][reg], sc[1][reg]), fmaxf(sc[2][reg], sc[3][reg]));
            mx = fmaxf(mx, __shfl_xor(mx, 1, 64));
            mx = fmaxf(mx, __shfl_xor(mx, 2, 64));
            mx = fmaxf(mx, __shfl_xor(mx, 4, 64));
            mx = fmaxf(mx, __shfl_xor(mx, 8, 64));
            float mnew = fmaxf(mrow[reg], mx);
            float alpha = __expf(mrow[reg] - mnew);
            mrow[reg] = mnew;
            float ps = 0.f;
            #pragma unroll
            for (int ct = 0; ct < 4; ++ct) {
                float p = __expf(sc[ct][reg] - mnew);
                sc[ct][reg] = p;
                ps += p;
            }
            ps += __shfl_xor(ps, 1, 64);
            ps += __shfl_xor(ps, 2, 64);
            ps += __shfl_xor(ps, 4, 64);
            ps += __shfl_xor(ps, 8, 64);
            lrow[reg] = lrow[reg] * alpha + ps;
            #pragma unroll
            for (int dt = 0; dt < 4; ++dt) oacc[dt][reg] *= alpha;
        }

        // ---- P -> LDS bf16 (swizzled) ----
        #pragma unroll
        for (int ct = 0; ct < 4; ++ct)
            #pragma unroll
            for (int reg = 0; reg < 4; ++reg) {
                int row = 4 * g + reg, col = 16 * ct + l15;
                *(ushort*)(pswb[w] + swz(row, col * 2)) = f2bf(sc[ct][reg]);
            }
        asm volatile("" ::: "memory");

        // ---- PV ----
        bf16x8 pf[2];
        #pragma unroll
        for (int ks = 0; ks < 2; ++ks)
            pf[ks] = *(const bf16x8*)(pswb[w] + swz(l15, (4 * ks + g) * 16));
        #pragma unroll
        for (int dt = 0; dt < 4; ++dt) {
            #pragma unroll
            for (int ks = 0; ks < 2; ++ks) {
                bf16x8 vf = *(const bf16x8*)(vtsw + swz(16 * dt + l15, (4 * ks + g) * 16));
                oacc[dt] = mfma16(pf[ks], vf, oacc[dt]);
            }
        }
    }

    // ---- epilogue: normalize, store fp32 ----
    float inv[4];
    #pragma unroll
    for (int reg = 0; reg < 4; ++reg) inv[reg] = 1.f / lrow[reg];
    float* obase = ob + (size_t)(b * NSEQ + n0 + w * 16) * INNER + h * DHEAD;
    #pragma unroll
    for (int dt = 0; dt < 4; ++dt)
        #pragma unroll
        for (int reg = 0; reg < 4; ++reg)
            obase[(size_t)(4 * g + reg) * INNER + 16 * dt + l15] = oacc[dt][reg] * inv[reg];
}

// ---------------------------------------------------------------------------
extern "C" void kernel_launch(void* const* d_in, const int* in_sizes, int n_in,
                              void* d_out, int out_size, void* d_ws, size_t ws_size,
                              hipStream_t stream)
{
    const float* x   = (const float*)d_in[0];
    const float* Wq  = (const float*)d_in[1];
    const float* Wkv = (const float*)d_in[2];
    const float* Wo  = (const float*)d_in[3];
    const float* bo  = (const float*)d_in[4];
    const float* rel = (const float*)d_in[5];
    float* out = (float*)d_out;

    const size_t ROWS = (size_t)BATCH * NSEQ;        // 8192
    ushort* qbuf  = (ushort*)d_ws;                   // [8192, 512] bf16
    ushort* kbuf  = qbuf + ROWS * INNER;             // [8192, 512] bf16
    ushort* vtbuf = kbuf + ROWS * INNER;             // [B, H, 64, 2048] bf16
    ushort* relb  = vtbuf + ROWS * INNER;            // [1025, 64] bf16
    float*  abuf  = (float*)(relb + (2 * MAXPOS + 1) * DHEAD);  // [8192, 512] f32

    dim3 blk(256);

    rel2bf_kernel<<<dim3(((2 * MAXPOS + 1) * DHEAD + 255) / 256), blk, 0, stream>>>(rel, relb);

    // q = (x @ Wq) * SCALE -> bf16
    gemm_kernel<1><<<dim3(INNER / 64, ROWS / 64), blk, 0, stream>>>(
        x, Wq, nullptr, qbuf, nullptr, (int)ROWS, DIM, INNER, nullptr, SCALE);
    // kv = x @ Wkv -> bf16 K row-major + V transposed
    gemm_kernel<2><<<dim3(2 * INNER / 64, ROWS / 64), blk, 0, stream>>>(
        x, Wkv, nullptr, kbuf, vtbuf, (int)ROWS, DIM, 2 * INNER, nullptr, 1.0f);
    // attention
    flash_mfma_kernel<<<dim3(NSEQ / 64, HEADS, BATCH), blk, 0, stream>>>(
        qbuf, kbuf, vtbuf, relb, abuf);
    // out = abuf @ Wo + bo (fp32)
    gemm_kernel<0><<<dim3(DIM / 64, ROWS / 64), blk, 0, stream>>>(
        abuf, Wo, out, nullptr, nullptr, (int)ROWS, INNER, DIM, bo, 1.0f);
}

// Round 4
// 402.309 us; speedup vs baseline: 7.1860x; 1.4447x over previous
//
#include <hip/hip_runtime.h>
#include <cstddef>
#include <cstdint>

#define HEADS   8
#define DHEAD   64
#define MAXPOS  512
#define DIM     512
#define INNER   512
#define NSEQ    2048
#define BATCH   4
#define ROWS    (BATCH * NSEQ)   // 8192

static constexpr float SCALE = 0.125f;  // DIM_HEAD^-0.5

typedef __bf16 bf16x8 __attribute__((ext_vector_type(8)));
typedef float  f32x4  __attribute__((ext_vector_type(4)));

static __device__ __forceinline__ ushort f2bf(float f) {
    union { float f; unsigned u; } v; v.f = f;
    unsigned r = v.u + 0x7FFFu + ((v.u >> 16) & 1u);   // RTNE
    return (ushort)(r >> 16);
}
static __device__ __forceinline__ float bf2f(ushort u) {
    union { unsigned u; float f; } v; v.u = ((unsigned)u) << 16;
    return v.f;
}
static __device__ __forceinline__ f32x4 mfma16(bf16x8 a, bf16x8 b, f32x4 c) {
    return __builtin_amdgcn_mfma_f32_16x16x32_bf16(a, b, c, 0, 0, 0);
}
static __device__ __forceinline__ void gload16(const void* g, void* l) {
    __builtin_amdgcn_global_load_lds(
        (const __attribute__((address_space(1))) void*)g,
        (__attribute__((address_space(3))) void*)l, 16, 0, 0);
}
// swizzled byte offset within a 128B-row LDS tile
static __device__ __forceinline__ int swz(int row, int byteoff) {
    return row * 128 + (byteoff ^ ((row & 7) << 4));
}

// ---------------------------------------------------------------------------
// Prep kernels (proven f2bf path)
// ---------------------------------------------------------------------------
__global__ __launch_bounds__(256) void convx_kernel(const float* __restrict__ x,
                                                    ushort* __restrict__ xb)
{
    size_t i = ((size_t)blockIdx.x * 256 + threadIdx.x) * 8;
    float4 a = *(const float4*)(x + i);
    float4 b = *(const float4*)(x + i + 4);
    ushort4 o0 = make_ushort4(f2bf(a.x), f2bf(a.y), f2bf(a.z), f2bf(a.w));
    ushort4 o1 = make_ushort4(f2bf(b.x), f2bf(b.y), f2bf(b.z), f2bf(b.w));
    *(ushort4*)(xb + i) = o0;
    *(ushort4*)(xb + i + 4) = o1;
}

__global__ __launch_bounds__(256) void convrel_kernel(const float* __restrict__ rel,
                                                      ushort* __restrict__ relb)
{
    int i = blockIdx.x * 256 + threadIdx.x;
    if (i < (2 * MAXPOS + 1) * DHEAD) relb[i] = f2bf(rel[i]);
}

// W [512][N] fp32 -> WT [N][512] bf16
__global__ __launch_bounds__(256) void transw_kernel(const float* __restrict__ W,
                                                     ushort* __restrict__ WT, int N)
{
    __shared__ float t[64][65];
    const int n0 = blockIdx.x * 64, k0 = blockIdx.y * 64;
    const int c = threadIdx.x & 63, r4 = threadIdx.x >> 6;
    #pragma unroll
    for (int i = 0; i < 16; ++i) {
        int k = i * 4 + r4;
        t[k][c] = W[(size_t)(k0 + k) * N + n0 + c];
    }
    __syncthreads();
    #pragma unroll
    for (int i = 0; i < 16; ++i) {
        int n = i * 4 + r4;
        WT[(size_t)(n0 + n) * 512 + k0 + c] = f2bf(t[c][n]);
    }
}

// ---------------------------------------------------------------------------
// bf16 MFMA projection GEMM (the NEW piece under test this round).
// C[m][n] = A[8192,512] @ WT[N,512]^T ; BM=128 BN=64 BK=64, 4 waves.
// MODE 0: bf16 out * scale (Q).  MODE 1: KV split (K row-major / V^T).
// ---------------------------------------------------------------------------
template <int MODE>
__global__ __launch_bounds__(256, 4) void gemmb_kernel(
    const ushort* __restrict__ A, const ushort* __restrict__ BT,
    ushort* __restrict__ C0, ushort* __restrict__ C1, float scale)
{
    __shared__ __attribute__((aligned(16))) char gl[24576];  // As 16K | Bs 8K

    const int tid = threadIdx.x;
    const int w = tid >> 6;
    const int lane = tid & 63;
    const int l15 = lane & 15;
    const int g = lane >> 4;
    const int sw = (l15 & 7) << 4;
    const int m0 = blockIdx.y * 128;
    const int n0 = blockIdx.x * 64;

    const int srow = tid >> 3;
    const int sel = (tid & 7) ^ (srow & 7);

    const ushort* asrc[4];
    #pragma unroll
    for (int it = 0; it < 4; ++it)
        asrc[it] = A + (size_t)(m0 + it * 32 + srow) * 512 + sel * 8;
    const ushort* bsrc[2];
    #pragma unroll
    for (int it = 0; it < 2; ++it)
        bsrc[it] = BT + (size_t)(n0 + it * 32 + srow) * 512 + sel * 8;

    f32x4 acc[2][4];
    #pragma unroll
    for (int mt = 0; mt < 2; ++mt)
        #pragma unroll
        for (int nt = 0; nt < 4; ++nt) acc[mt][nt] = (f32x4){0.f, 0.f, 0.f, 0.f};

    for (int k0 = 0; k0 < 512; k0 += 64) {
        if (k0) __syncthreads();
        #pragma unroll
        for (int it = 0; it < 4; ++it)
            gload16(asrc[it] + k0, gl + (it * 256 + tid) * 16);
        #pragma unroll
        for (int it = 0; it < 2; ++it)
            gload16(bsrc[it] + k0, gl + 16384 + (it * 256 + tid) * 16);
        __syncthreads();

        #pragma unroll
        for (int ks = 0; ks < 2; ++ks) {
            const int ko = (64 * ks + 16 * g) ^ sw;
            bf16x8 a0 = *(const bf16x8*)(gl + (32 * w + l15) * 128 + ko);
            bf16x8 a1 = *(const bf16x8*)(gl + (32 * w + 16 + l15) * 128 + ko);
            #pragma unroll
            for (int nt = 0; nt < 4; ++nt) {
                bf16x8 bb = *(const bf16x8*)(gl + 16384 + (16 * nt + l15) * 128 + ko);
                acc[0][nt] = mfma16(a0, bb, acc[0][nt]);
                acc[1][nt] = mfma16(a1, bb, acc[1][nt]);
            }
        }
    }

    if (MODE == 0 || n0 < 512) {
        #pragma unroll
        for (int mt = 0; mt < 2; ++mt)
            #pragma unroll
            for (int nt = 0; nt < 4; ++nt)
                #pragma unroll
                for (int r = 0; r < 4; ++r) {
                    int m = m0 + 32 * w + 16 * mt + 4 * g + r;
                    int n = n0 + 16 * nt + l15;
                    C0[(size_t)m * 512 + n] = f2bf(acc[mt][nt][r] * scale);
                }
    } else {
        // V^T epilogue: per-wave 64x32 transpose via LDS, coalesced row writes
        __syncthreads();
        ushort* tw = (ushort*)gl + w * 2560;   // [64][40]
        #pragma unroll
        for (int mt = 0; mt < 2; ++mt)
            #pragma unroll
            for (int nt = 0; nt < 4; ++nt)
                #pragma unroll
                for (int r = 0; r < 4; ++r)
                    tw[(16 * nt + l15) * 40 + 16 * mt + 4 * g + r] = f2bf(acc[mt][nt][r]);
        asm volatile("" ::: "memory");
        const int hh = (n0 - 512) >> 6;
        const int bb = m0 >> 11;
        ushort* dbase = C1 + ((size_t)bb * HEADS + hh) * DHEAD * NSEQ + (m0 & 2047) + 32 * w;
        #pragma unroll
        for (int p = 0; p < 4; ++p) {
            int row = p * 16 + (lane >> 2);
            int slot = lane & 3;
            *(int4*)(dbase + (size_t)row * NSEQ + slot * 8) =
                *(const int4*)(tw + row * 40 + slot * 8);
        }
    }
}

// ---------------------------------------------------------------------------
// fp32 GEMM for the output projection (proven)
// ---------------------------------------------------------------------------
__global__ __launch_bounds__(256) void gemmf_kernel(
    const float* __restrict__ A, const float* __restrict__ W,
    float* __restrict__ C, int M, int K, int Nc,
    const float* __restrict__ bias)
{
    __shared__ float As[16][68];
    __shared__ float Ws[16][68];

    const int tid = threadIdx.x;
    const int tx = tid & 15;
    const int ty = tid >> 4;
    const int m0 = blockIdx.y * 64;
    const int n0 = blockIdx.x * 64;

    float acc[4][4] = {};

    for (int k0 = 0; k0 < K; k0 += 16) {
        #pragma unroll
        for (int i = 0; i < 4; ++i) {
            int e = i * 256 + tid;
            int m = e >> 4, k = e & 15;
            As[k][m] = A[(size_t)(m0 + m) * K + (k0 + k)];
        }
        #pragma unroll
        for (int i = 0; i < 4; ++i) {
            int e = i * 256 + tid;
            int k = e >> 6, n = e & 63;
            Ws[k][n] = W[(size_t)(k0 + k) * Nc + (n0 + n)];
        }
        __syncthreads();
        #pragma unroll
        for (int kk = 0; kk < 16; ++kk) {
            float4 a = *(const float4*)&As[kk][ty * 4];
            float4 w = *(const float4*)&Ws[kk][tx * 4];
            acc[0][0] += a.x * w.x; acc[0][1] += a.x * w.y; acc[0][2] += a.x * w.z; acc[0][3] += a.x * w.w;
            acc[1][0] += a.y * w.x; acc[1][1] += a.y * w.y; acc[1][2] += a.y * w.z; acc[1][3] += a.y * w.w;
            acc[2][0] += a.z * w.x; acc[2][1] += a.z * w.y; acc[2][2] += a.z * w.z; acc[2][3] += a.z * w.w;
            acc[3][0] += a.w * w.x; acc[3][1] += a.w * w.y; acc[3][2] += a.w * w.z; acc[3][3] += a.w * w.w;
        }
        __syncthreads();
    }

    float4 b4 = *(const float4*)&bias[n0 + tx * 4];
    #pragma unroll
    for (int i = 0; i < 4; ++i) {
        float4 r;
        r.x = acc[i][0] + b4.x;
        r.y = acc[i][1] + b4.y;
        r.z = acc[i][2] + b4.z;
        r.w = acc[i][3] + b4.w;
        *(float4*)&C[(size_t)(m0 + ty * 4 + i) * Nc + n0 + tx * 4] = r;
    }
}

// ---------------------------------------------------------------------------
// MFMA flash attention with relative positions — VERBATIM round-2 (proven).
// ---------------------------------------------------------------------------
__global__ __launch_bounds__(256, 2) void flash_mfma_kernel(
    const ushort* __restrict__ qb,    // [B*N, 512] bf16, pre-scaled by SCALE
    const ushort* __restrict__ kb,    // [B*N, 512] bf16
    const ushort* __restrict__ vtb,   // [B, H, 64, N] bf16 (V transposed)
    const ushort* __restrict__ relb,  // [1025, 64] bf16
    float* __restrict__ ob)           // [B*N, 512] f32
{
    __shared__ __attribute__((aligned(16))) char ksw[64 * 128];     // K tile
    __shared__ __attribute__((aligned(16))) char vtsw[64 * 128];    // V^T tile
    __shared__ __attribute__((aligned(16))) char relw[144 * 128];   // rel window
    __shared__ __attribute__((aligned(16))) char pswb[4][16 * 128]; // P per wave
    __shared__ ushort prs[4][16][100];                              // PR per wave

    const int tid  = threadIdx.x;
    const int w    = tid >> 6;
    const int lane = tid & 63;
    const int l15  = lane & 15;
    const int g    = lane >> 4;

    const int n0 = blockIdx.x * 64;
    const int h  = blockIdx.y;
    const int b  = blockIdx.z;

    bf16x8 qf[2];
    {
        const int nq = n0 + w * 16 + l15;
        const ushort* qrow = qb + (size_t)(b * NSEQ + nq) * INNER + h * DHEAD;
        qf[0] = *(const bf16x8*)(qrow + 8 * g);
        qf[1] = *(const bf16x8*)(qrow + 32 + 8 * g);
    }

    const ushort* kbase  = kb + (size_t)(b * NSEQ) * INNER + h * DHEAD;
    const ushort* vtbase = vtb + (size_t)(b * HEADS + h) * DHEAD * NSEQ;

    f32x4 oacc[4];
    #pragma unroll
    for (int i = 0; i < 4; ++i) oacc[i] = (f32x4){0.f, 0.f, 0.f, 0.f};
    float mrow[4] = {-1e30f, -1e30f, -1e30f, -1e30f};
    float lrow[4] = {0.f, 0.f, 0.f, 0.f};

    for (int kt = 0; kt < NSEQ / 64; ++kt) {
        const int r0 = kt * 64;
        int dlo = n0 - r0 - 63, dhi = n0 + 63 - r0;
        int jlo = min(max(dlo, -MAXPOS), MAXPOS) + MAXPOS;
        int jhi = min(max(dhi, -MAXPOS), MAXPOS) + MAXPOS;
        int span = jhi - jlo + 1;
        int nrows = (span + 30) & ~15; if (nrows > 144) nrows = 144;

        __syncthreads();
        for (int c = tid; c < 512; c += 256) {
            int row = c >> 3, sl = c & 7;
            *(int4*)(ksw + swz(row, sl * 16)) =
                *(const int4*)(kbase + (size_t)(r0 + row) * INNER + sl * 8);
        }
        for (int c = tid; c < 512; c += 256) {
            int d = c >> 3, sl = c & 7;
            *(int4*)(vtsw + swz(d, sl * 16)) =
                *(const int4*)(vtbase + (size_t)d * NSEQ + r0 + sl * 8);
        }
        for (int c = tid; c < nrows * 8; c += 256) {
            int row = c >> 3, sl = c & 7;
            int gr = jlo + row; if (gr > 2 * MAXPOS) gr = 2 * MAXPOS;
            *(int4*)(relw + swz(row, sl * 16)) =
                *(const int4*)(relb + gr * DHEAD + sl * 8);
        }
        __syncthreads();

        // ---- QK^T ----
        f32x4 sc[4];
        #pragma unroll
        for (int ct = 0; ct < 4; ++ct) {
            f32x4 a = (f32x4){0.f, 0.f, 0.f, 0.f};
            #pragma unroll
            for (int ks = 0; ks < 2; ++ks) {
                bf16x8 kf = *(const bf16x8*)(ksw + swz(16 * ct + l15, (4 * ks + g) * 16));
                a = mfma16(qf[ks], kf, a);
            }
            sc[ct] = a;
        }

        // ---- PR = Q · relwin^T over per-wave aligned sub-window ----
        const int nw0 = n0 + w * 16;
        int jlo_w = min(max(nw0 - r0 - 63, -MAXPOS), MAXPOS) + MAXPOS;
        int jhi_w = min(max(nw0 + 15 - r0, -MAXPOS), MAXPOS) + MAXPOS;
        int jbase = jlo + ((jlo_w - jlo) & ~15);
        int nct = (jhi_w - jbase + 16) >> 4;   // <= 6

        for (int c2 = 0; c2 < nct; ++c2) {
            f32x4 pr = (f32x4){0.f, 0.f, 0.f, 0.f};
            int wr = (jbase - jlo) + 16 * c2 + l15;
            #pragma unroll
            for (int ks = 0; ks < 2; ++ks) {
                bf16x8 rf = *(const bf16x8*)(relw + swz(wr, (4 * ks + g) * 16));
                pr = mfma16(qf[ks], rf, pr);
            }
            #pragma unroll
            for (int reg = 0; reg < 4; ++reg)
                prs[w][4 * g + reg][16 * c2 + l15] = f2bf(pr[reg]);
        }
        asm volatile("" ::: "memory");

        // ---- gather pos into scores ----
        #pragma unroll
        for (int ct = 0; ct < 4; ++ct) {
            int r = r0 + 16 * ct + l15;
            #pragma unroll
            for (int reg = 0; reg < 4; ++reg) {
                int n = nw0 + 4 * g + reg;
                int dd = min(max(n - r, -MAXPOS), MAXPOS) + MAXPOS;
                sc[ct][reg] += bf2f(prs[w][4 * g + reg][dd - jbase]);
            }
        }

        // ---- online softmax ----
        #pragma unroll
        for (int reg = 0; reg < 4; ++reg) {
            float mx = fmaxf(fmaxf(sc[0][reg], sc[1][reg]), fmaxf(sc[2][reg], sc[3][reg]));
            mx = fmaxf(mx, __shfl_xor(mx, 1, 64));
            mx = fmaxf(mx, __shfl_xor(mx, 2, 64));
            mx = fmaxf(mx, __shfl_xor(mx, 4, 64));
            mx = fmaxf(mx, __shfl_xor(mx, 8, 64));
            float mnew = fmaxf(mrow[reg], mx);
            float alpha = __expf(mrow[reg] - mnew);
            mrow[reg] = mnew;
            float ps = 0.f;
            #pragma unroll
            for (int ct = 0; ct < 4; ++ct) {
                float p = __expf(sc[ct][reg] - mnew);
                sc[ct][reg] = p;
                ps += p;
            }
            ps += __shfl_xor(ps, 1, 64);
            ps += __shfl_xor(ps, 2, 64);
            ps += __shfl_xor(ps, 4, 64);
            ps += __shfl_xor(ps, 8, 64);
            lrow[reg] = lrow[reg] * alpha + ps;
            #pragma unroll
            for (int dt = 0; dt < 4; ++dt) oacc[dt][reg] *= alpha;
        }

        // ---- P -> LDS bf16 (swizzled) ----
        #pragma unroll
        for (int ct = 0; ct < 4; ++ct)
            #pragma unroll
            for (int reg = 0; reg < 4; ++reg) {
                int row = 4 * g + reg, col = 16 * ct + l15;
                *(ushort*)(pswb[w] + swz(row, col * 2)) = f2bf(sc[ct][reg]);
            }
        asm volatile("" ::: "memory");

        // ---- PV ----
        bf16x8 pf[2];
        #pragma unroll
        for (int ks = 0; ks < 2; ++ks)
            pf[ks] = *(const bf16x8*)(pswb[w] + swz(l15, (4 * ks + g) * 16));
        #pragma unroll
        for (int dt = 0; dt < 4; ++dt) {
            #pragma unroll
            for (int ks = 0; ks < 2; ++ks) {
                bf16x8 vf = *(const bf16x8*)(vtsw + swz(16 * dt + l15, (4 * ks + g) * 16));
                oacc[dt] = mfma16(pf[ks], vf, oacc[dt]);
            }
        }
    }

    // ---- epilogue ----
    float inv[4];
    #pragma unroll
    for (int reg = 0; reg < 4; ++reg) inv[reg] = 1.f / lrow[reg];
    float* obase = ob + (size_t)(b * NSEQ + n0 + w * 16) * INNER + h * DHEAD;
    #pragma unroll
    for (int dt = 0; dt < 4; ++dt)
        #pragma unroll
        for (int reg = 0; reg < 4; ++reg)
            obase[(size_t)(4 * g + reg) * INNER + 16 * dt + l15] = oacc[dt][reg] * inv[reg];
}

// ---------------------------------------------------------------------------
extern "C" void kernel_launch(void* const* d_in, const int* in_sizes, int n_in,
                              void* d_out, int out_size, void* d_ws, size_t ws_size,
                              hipStream_t stream)
{
    const float* x   = (const float*)d_in[0];
    const float* Wq  = (const float*)d_in[1];
    const float* Wkv = (const float*)d_in[2];
    const float* Wo  = (const float*)d_in[3];
    const float* bo  = (const float*)d_in[4];
    const float* rel = (const float*)d_in[5];
    float* out = (float*)d_out;

    const size_t RI = (size_t)ROWS * INNER;           // 4,194,304
    ushort* xb    = (ushort*)d_ws;
    ushort* qbuf  = xb + RI;
    ushort* kbuf  = qbuf + RI;
    ushort* vtbuf = kbuf + RI;                        // [B,H,64,N]
    ushort* wqT   = vtbuf + RI;                       // [512][512]
    ushort* wkvT  = wqT + 512 * 512;                  // [1024][512]
    ushort* relb  = wkvT + 1024 * 512;                // [1025][64]
    float*  abuf  = (float*)(relb + 1056 * 64);       // [8192][512] f32 (pad keeps 16B align)

    dim3 blk(256);

    convx_kernel<<<dim3(2048), blk, 0, stream>>>(x, xb);
    convrel_kernel<<<dim3(((2 * MAXPOS + 1) * DHEAD + 255) / 256), blk, 0, stream>>>(rel, relb);
    transw_kernel<<<dim3(8, 8), blk, 0, stream>>>(Wq, wqT, 512);
    transw_kernel<<<dim3(16, 8), blk, 0, stream>>>(Wkv, wkvT, 1024);

    // q = (x @ Wq) * SCALE -> bf16
    gemmb_kernel<0><<<dim3(8, 64), blk, 0, stream>>>(xb, wqT, qbuf, nullptr, SCALE);
    // kv = x @ Wkv -> K bf16 row-major + V^T
    gemmb_kernel<1><<<dim3(16, 64), blk, 0, stream>>>(xb, wkvT, kbuf, vtbuf, 1.0f);
    // attention (round-2 proven kernel)
    flash_mfma_kernel<<<dim3(NSEQ / 64, HEADS, BATCH), blk, 0, stream>>>(
        qbuf, kbuf, vtbuf, relb, abuf);
    // out = abuf @ Wo + bo (fp32)
    gemmf_kernel<<<dim3(8, 128), blk, 0, stream>>>(abuf, Wo, out, ROWS, INNER, DIM, bo);
}